// Round 1
// baseline (136.922 us; speedup 1.0000x reference)
//
#include <hip/hip_runtime.h>

#define SS 160
#define DD 256
#define BB 8
#define NPAIR 12720            // S*(S-1)/2
#define M_TOT (BB * SS)        // 1280

// ---------------------------------------------------------------------------
// Kernel 1: fused double GEMM.
//   ya[m][e] = sum_d x[m][d] * W[d][e]       + bias[e]   (m = b*160+s)
//   yb[m][e] = sum_d x[m][d] * W[256+d][e]
// Treated as one M=1280, K=256, N=512 GEMM; columns >= 256 use the Wj half.
// BM=32, BN=64, BK=32, 256 threads, each thread computes 2 rows x 4 cols.
// ---------------------------------------------------------------------------
__global__ __launch_bounds__(256) void gemm_kernel(const float* __restrict__ x,
                                                   const float* __restrict__ W,
                                                   const float* __restrict__ bias,
                                                   float* __restrict__ y) {
    const int BM = 32, BN = 64, BK = 32;
    __shared__ float As[BK][BM + 1];   // transposed: As[k][m], +1 pad
    __shared__ float Bs[BK][BN];

    const int n0 = blockIdx.x * BN;          // 0..511 step 64 (stays in one half)
    const int m0 = blockIdx.y * BM;
    const int half = (n0 >= DD) ? 1 : 0;
    const float* Wbase = W + (half ? DD * DD : 0);
    const int ncol0 = n0 - (half ? DD : 0);

    const int tid = threadIdx.x;
    const int tx = tid & 15;            // col group: cols 4*tx..4*tx+3
    const int ty = tid >> 4;            // rows ty and ty+16

    // global loader mapping
    const int ar = tid >> 3;            // A row 0..31
    const int ac = (tid & 7) << 2;      // A col 0..28 step 4
    const int bkr = tid >> 4;           // B k-row 0..15 (and +16)
    const int bnc = (tid & 15) << 2;    // B col 0..60 step 4

    float acc0[4] = {0.f, 0.f, 0.f, 0.f};
    float acc1[4] = {0.f, 0.f, 0.f, 0.f};

    for (int k0 = 0; k0 < DD; k0 += BK) {
        float4 av = *(const float4*)(x + (m0 + ar) * DD + k0 + ac);
        float4 b0 = *(const float4*)(Wbase + (k0 + bkr) * DD + ncol0 + bnc);
        float4 b1 = *(const float4*)(Wbase + (k0 + bkr + 16) * DD + ncol0 + bnc);
        __syncthreads();                         // previous tile's reads done
        As[ac + 0][ar] = av.x;
        As[ac + 1][ar] = av.y;
        As[ac + 2][ar] = av.z;
        As[ac + 3][ar] = av.w;
        *(float4*)(&Bs[bkr][bnc])      = b0;
        *(float4*)(&Bs[bkr + 16][bnc]) = b1;
        __syncthreads();
#pragma unroll
        for (int kk = 0; kk < BK; ++kk) {
            float a0 = As[kk][ty];
            float a1 = As[kk][ty + 16];
            float4 bv = *(const float4*)(&Bs[kk][tx << 2]);
            acc0[0] += a0 * bv.x; acc0[1] += a0 * bv.y;
            acc0[2] += a0 * bv.z; acc0[3] += a0 * bv.w;
            acc1[0] += a1 * bv.x; acc1[1] += a1 * bv.y;
            acc1[2] += a1 * bv.z; acc1[3] += a1 * bv.w;
        }
    }

    float4 bias4 = make_float4(0.f, 0.f, 0.f, 0.f);
    if (!half) bias4 = *(const float4*)(bias + ncol0 + (tx << 2));   // bias folded into ya only

    float* yout = y + (half ? M_TOT * DD : 0);
    float4 r0, r1;
    r0.x = acc0[0] + bias4.x; r0.y = acc0[1] + bias4.y;
    r0.z = acc0[2] + bias4.z; r0.w = acc0[3] + bias4.w;
    r1.x = acc1[0] + bias4.x; r1.y = acc1[1] + bias4.y;
    r1.z = acc1[2] + bias4.z; r1.w = acc1[3] + bias4.w;
    *(float4*)(yout + (m0 + ty) * DD + ncol0 + (tx << 2))      = r0;
    *(float4*)(yout + (m0 + ty + 16) * DD + ncol0 + (tx << 2)) = r1;
}

// ---------------------------------------------------------------------------
// Kernel 2: pair expansion. One 64-lane wave per output row (256 floats =
// 64 float4). out[b,p,:] = ya[b,i_p,:] + yb[b,j_p,:]  (bias already in ya).
// (i,j) recovered from p via closed-form triangular-index inversion + fixup;
// wave-uniform, a few cycles vs 1 KB of stores.
// ---------------------------------------------------------------------------
__global__ __launch_bounds__(256) void expand_kernel(const float* __restrict__ y,
                                                     float* __restrict__ out) {
    const int row  = (blockIdx.x << 2) + (threadIdx.x >> 6);   // 0..101759
    const int lane = threadIdx.x & 63;
    const unsigned b = (unsigned)row / NPAIR;
    const int p = row - (int)b * NPAIR;

    // i = floor((2S-1 - sqrt((2S-1)^2 - 8p)) / 2); offset(i) = i*(2S-1-i)/2
    float disc = sqrtf((float)(101761 - 8 * p));     // (2*160-1)^2 = 101761
    int i = (int)((319.0f - disc) * 0.5f);
    if (i < 0) i = 0;
    if (i > SS - 2) i = SS - 2;
    while (i > 0 && (i * (2 * SS - 1 - i)) / 2 > p) --i;
    while (((i + 1) * (2 * SS - 2 - i)) / 2 <= p) ++i;
    const int j = i + 1 + p - (i * (2 * SS - 1 - i)) / 2;

    const float4* ya = (const float4*)y;
    const float4* yb = (const float4*)(y + M_TOT * DD);
    float4 va = ya[(((int)b * SS + i) << 6) + lane];
    float4 vb = yb[(((int)b * SS + j) << 6) + lane];
    float4 r;
    r.x = va.x + vb.x; r.y = va.y + vb.y;
    r.z = va.z + vb.z; r.w = va.w + vb.w;
    ((float4*)out)[(row << 6) + lane] = r;
}

extern "C" void kernel_launch(void* const* d_in, const int* in_sizes, int n_in,
                              void* d_out, int out_size, void* d_ws, size_t ws_size,
                              hipStream_t stream) {
    const float* x    = (const float*)d_in[0];   // (8,160,256)
    const float* W    = (const float*)d_in[1];   // (512,256)
    const float* bias = (const float*)d_in[2];   // (256,)
    float* y   = (float*)d_ws;                   // ya[1280*256] then yb[1280*256]
    float* out = (float*)d_out;                  // (8,12720,256)

    dim3 gemm_grid(512 / 64, 1280 / 32);         // 8 x 40 = 320 blocks
    gemm_kernel<<<gemm_grid, 256, 0, stream>>>(x, W, bias, y);

    const int rows = BB * NPAIR;                 // 101760
    expand_kernel<<<rows / 4, 256, 0, stream>>>(y, out);
}

// Round 2
// 129.940 us; speedup vs baseline: 1.0537x; 1.0537x over previous
//
#include <hip/hip_runtime.h>

#define SS 160
#define DD 256
#define BB 8
#define NPAIR 12720            // S*(S-1)/2
#define M_TOT (BB * SS)        // 1280

// ---------------------------------------------------------------------------
// Kernel 1: fused double GEMM, 64x64 tile, BK=32, 4x4 register blocking.
//   ya[m][e] = sum_d x[m][d] * W[d][e]       + bias[e]   (m = b*160+s)
//   yb[m][e] = sum_d x[m][d] * W[256+d][e]
// One M=1280, K=256, N=512 GEMM; cols >= 256 use the Wj half (no bias).
// Grid (8, 20) = 160 blocks x 256 threads. Each thread: 4 rows x 4 cols.
// Inner: 2 x ds_read_b128 -> 16 FMA  (2 FMA/dword; As reads broadcast).
// ---------------------------------------------------------------------------
__global__ __launch_bounds__(256) void gemm_kernel(const float* __restrict__ x,
                                                   const float* __restrict__ W,
                                                   const float* __restrict__ bias,
                                                   float* __restrict__ y) {
    const int BM = 64, BN = 64, BK = 32;
    __shared__ float As[BK][BM + 4];   // transposed: As[k][m]; +4 keeps 16B align, breaks write conflicts
    __shared__ float Bs[BK][BN];

    const int n0 = blockIdx.x * BN;          // 0..511 step 64 (stays in one half)
    const int m0 = blockIdx.y * BM;
    const int half = (n0 >= DD) ? 1 : 0;
    const float* Wbase = W + (half ? DD * DD : 0);
    const int ncol0 = n0 - (half ? DD : 0);

    const int tid = threadIdx.x;
    const int tx = tid & 15;            // col group: cols 4*tx..4*tx+3
    const int ty = tid >> 4;            // row group: rows 4*ty..4*ty+3

    // global loader mapping
    const int ar = tid & 63;            // A row 0..63
    const int ak = (tid >> 6) << 3;     // A k-offset {0,8,16,24}, loads 8 floats
    const int bk = tid >> 3;            // B k-row 0..31
    const int bc = (tid & 7) << 3;      // B col {0,8,...,56}, loads 8 floats

    float4 acc[4];
#pragma unroll
    for (int r = 0; r < 4; ++r) acc[r] = make_float4(0.f, 0.f, 0.f, 0.f);

    for (int k0 = 0; k0 < DD; k0 += BK) {
        float4 a0 = *(const float4*)(x + (m0 + ar) * DD + k0 + ak);
        float4 a1 = *(const float4*)(x + (m0 + ar) * DD + k0 + ak + 4);
        float4 b0 = *(const float4*)(Wbase + (k0 + bk) * DD + ncol0 + bc);
        float4 b1 = *(const float4*)(Wbase + (k0 + bk) * DD + ncol0 + bc + 4);
        __syncthreads();                         // previous tile's reads done
        As[ak + 0][ar] = a0.x; As[ak + 1][ar] = a0.y;
        As[ak + 2][ar] = a0.z; As[ak + 3][ar] = a0.w;
        As[ak + 4][ar] = a1.x; As[ak + 5][ar] = a1.y;
        As[ak + 6][ar] = a1.z; As[ak + 7][ar] = a1.w;
        *(float4*)(&Bs[bk][bc])     = b0;
        *(float4*)(&Bs[bk][bc + 4]) = b1;
        __syncthreads();
#pragma unroll
        for (int kk = 0; kk < BK; ++kk) {
            float4 av = *(const float4*)(&As[kk][ty << 2]);
            float4 bv = *(const float4*)(&Bs[kk][tx << 2]);
            acc[0].x += av.x * bv.x; acc[0].y += av.x * bv.y;
            acc[0].z += av.x * bv.z; acc[0].w += av.x * bv.w;
            acc[1].x += av.y * bv.x; acc[1].y += av.y * bv.y;
            acc[1].z += av.y * bv.z; acc[1].w += av.y * bv.w;
            acc[2].x += av.z * bv.x; acc[2].y += av.z * bv.y;
            acc[2].z += av.z * bv.z; acc[2].w += av.z * bv.w;
            acc[3].x += av.w * bv.x; acc[3].y += av.w * bv.y;
            acc[3].z += av.w * bv.z; acc[3].w += av.w * bv.w;
        }
    }

    float4 bias4 = make_float4(0.f, 0.f, 0.f, 0.f);
    if (!half) bias4 = *(const float4*)(bias + ncol0 + (tx << 2));  // bias folded into ya only

    float* yout = y + (half ? M_TOT * DD : 0);
#pragma unroll
    for (int r = 0; r < 4; ++r) {
        float4 v;
        v.x = acc[r].x + bias4.x; v.y = acc[r].y + bias4.y;
        v.z = acc[r].z + bias4.z; v.w = acc[r].w + bias4.w;
        *(float4*)(yout + (m0 + (ty << 2) + r) * DD + ncol0 + (tx << 2)) = v;
    }
}

// ---------------------------------------------------------------------------
// Kernel 2: pair expansion, block per (i, b). Grid (159, 8), 256 threads.
// Block loads ya[b,i] once (per-lane float4 in registers), then the 4 waves
// stream rows j = i+1+r (r = wave, step 4):
//   out[b, offset(i)+r, :] = va + yb[b, i+1+r, :]
// No per-row index math; loads independent -> deep unroll; 1KB coalesced
// stores per row. offset(i) = i*(2S-1-i)/2.
// ---------------------------------------------------------------------------
__global__ __launch_bounds__(256) void expand_kernel(const float* __restrict__ y,
                                                     float* __restrict__ out) {
    const int i = blockIdx.x;              // 0..158
    const int b = blockIdx.y;              // 0..7
    const int w = threadIdx.x >> 6;        // wave 0..3
    const int lane = threadIdx.x & 63;
    const int L = SS - 1 - i;              // number of rows for this i

    const float4* ya = (const float4*)y;
    const float4* yb = (const float4*)(y + M_TOT * DD);
    const float4 va = ya[((b * SS + i) << 6) + lane];

    const float4* ybb = yb + (((b * SS + i + 1) << 6) + lane);   // row r at ybb[r<<6]
    float4* ob = (float4*)out + (((b * NPAIR + (i * (2 * SS - 1 - i)) / 2) << 6) + lane);

#pragma unroll 4
    for (int r = w; r < L; r += 4) {
        float4 vb = ybb[r << 6];
        float4 o;
        o.x = va.x + vb.x; o.y = va.y + vb.y;
        o.z = va.z + vb.z; o.w = va.w + vb.w;
        ob[r << 6] = o;
    }
}

extern "C" void kernel_launch(void* const* d_in, const int* in_sizes, int n_in,
                              void* d_out, int out_size, void* d_ws, size_t ws_size,
                              hipStream_t stream) {
    const float* x    = (const float*)d_in[0];   // (8,160,256)
    const float* W    = (const float*)d_in[1];   // (512,256)
    const float* bias = (const float*)d_in[2];   // (256,)
    float* y   = (float*)d_ws;                   // ya[1280*256] then yb[1280*256]
    float* out = (float*)d_out;                  // (8,12720,256)

    dim3 gemm_grid(512 / 64, 1280 / 64);         // 8 x 20 = 160 blocks
    gemm_kernel<<<gemm_grid, 256, 0, stream>>>(x, W, bias, y);

    dim3 exp_grid(SS - 1, BB);                   // 159 x 8 blocks
    expand_kernel<<<exp_grid, 256, 0, stream>>>(y, out);
}

// Round 3
// 127.973 us; speedup vs baseline: 1.0699x; 1.0154x over previous
//
#include <hip/hip_runtime.h>

#define SS 160
#define DD 256
#define BB 8
#define NPAIR 12720            // S*(S-1)/2
#define M_TOT (BB * SS)        // 1280
#define TOTROWS (BB * NPAIR)   // 101760
#define NWAVES 8192            // 2048 blocks x 4 waves = 8 waves/SIMD device-wide

// ---------------------------------------------------------------------------
// Kernel 1: fused double GEMM. BM=32, BN=64, BK=32 -> grid (8,40)=320 blocks,
// every CU busy. Each thread: 2 rows x 4 cols.
//   ya[m][e] = x[m][:] @ W[:256][e] + bias[e]
//   yb[m][e] = x[m][:] @ W[256:][e]
// ---------------------------------------------------------------------------
__global__ __launch_bounds__(256) void gemm_kernel(const float* __restrict__ x,
                                                   const float* __restrict__ W,
                                                   const float* __restrict__ bias,
                                                   float* __restrict__ y) {
    const int BM = 32, BN = 64, BK = 32;
    __shared__ float As[BK][BM + 1];   // transposed: As[k][m], +1 pad
    __shared__ float Bs[BK][BN];

    const int n0 = blockIdx.x * BN;          // 0..511 step 64 (stays in one half)
    const int m0 = blockIdx.y * BM;
    const int half = (n0 >= DD) ? 1 : 0;
    const float* Wbase = W + (half ? DD * DD : 0);
    const int ncol0 = n0 - (half ? DD : 0);

    const int tid = threadIdx.x;
    const int tx = tid & 15;            // col group: cols 4*tx..4*tx+3
    const int ty = tid >> 4;            // rows ty and ty+16

    // global loader mapping
    const int ar = tid >> 3;            // A row 0..31
    const int ac = (tid & 7) << 2;      // A col 0..28 step 4
    const int bkr = tid >> 4;           // B k-row 0..15 (and +16)
    const int bnc = (tid & 15) << 2;    // B col 0..60 step 4

    float acc0[4] = {0.f, 0.f, 0.f, 0.f};
    float acc1[4] = {0.f, 0.f, 0.f, 0.f};

    for (int k0 = 0; k0 < DD; k0 += BK) {
        float4 av = *(const float4*)(x + (m0 + ar) * DD + k0 + ac);
        float4 b0 = *(const float4*)(Wbase + (k0 + bkr) * DD + ncol0 + bnc);
        float4 b1 = *(const float4*)(Wbase + (k0 + bkr + 16) * DD + ncol0 + bnc);
        __syncthreads();                         // previous tile's reads done
        As[ac + 0][ar] = av.x;
        As[ac + 1][ar] = av.y;
        As[ac + 2][ar] = av.z;
        As[ac + 3][ar] = av.w;
        *(float4*)(&Bs[bkr][bnc])      = b0;
        *(float4*)(&Bs[bkr + 16][bnc]) = b1;
        __syncthreads();
#pragma unroll
        for (int kk = 0; kk < BK; ++kk) {
            float a0 = As[kk][ty];
            float a1 = As[kk][ty + 16];
            float4 bv = *(const float4*)(&Bs[kk][tx << 2]);
            acc0[0] += a0 * bv.x; acc0[1] += a0 * bv.y;
            acc0[2] += a0 * bv.z; acc0[3] += a0 * bv.w;
            acc1[0] += a1 * bv.x; acc1[1] += a1 * bv.y;
            acc1[2] += a1 * bv.z; acc1[3] += a1 * bv.w;
        }
    }

    float4 bias4 = make_float4(0.f, 0.f, 0.f, 0.f);
    if (!half) bias4 = *(const float4*)(bias + ncol0 + (tx << 2));   // bias folded into ya only

    float* yout = y + (half ? M_TOT * DD : 0);
    float4 r0, r1;
    r0.x = acc0[0] + bias4.x; r0.y = acc0[1] + bias4.y;
    r0.z = acc0[2] + bias4.z; r0.w = acc0[3] + bias4.w;
    r1.x = acc1[0] + bias4.x; r1.y = acc1[1] + bias4.y;
    r1.z = acc1[2] + bias4.z; r1.w = acc1[3] + bias4.w;
    *(float4*)(yout + (m0 + ty) * DD + ncol0 + (tx << 2))      = r0;
    *(float4*)(yout + (m0 + ty + 16) * DD + ncol0 + (tx << 2)) = r1;
}

// ---------------------------------------------------------------------------
// Kernel 2: balanced pair expansion. NWAVES waves, each takes a contiguous
// slice of the 101760 output rows (12-13 rows each -> zero imbalance).
// (b,i,j) derived once per wave (closed-form tri-index inversion), then
// advanced incrementally (wave-uniform). va (= ya row, bias included)
// reloaded from L2 only when i changes.
// ---------------------------------------------------------------------------
__global__ __launch_bounds__(256) void expand_kernel(const float* __restrict__ y,
                                                     float* __restrict__ out) {
    const int gw   = (blockIdx.x << 2) + (threadIdx.x >> 6);   // 0..NWAVES-1
    const int lane = threadIdx.x & 63;

    int r0 = (int)(((long long)gw * TOTROWS) / NWAVES);
    int r1 = (int)(((long long)(gw + 1) * TOTROWS) / NWAVES);

    int b = (unsigned)r0 / NPAIR;
    int p = r0 - b * NPAIR;

    // invert p -> (i,j): offset(i) = i*(2S-1-i)/2, j = i+1 + (p - offset(i))
    float disc = sqrtf((float)(101761 - 8 * p));     // (2S-1)^2 = 101761
    int i = (int)((319.0f - disc) * 0.5f);
    if (i < 0) i = 0;
    if (i > SS - 2) i = SS - 2;
    while (i > 0 && (i * (2 * SS - 1 - i)) / 2 > p) --i;
    while (((i + 1) * (2 * SS - 2 - i)) / 2 <= p) ++i;
    int j = i + 1 + p - (i * (2 * SS - 1 - i)) / 2;

    const float4* ya4 = (const float4*)y;
    const float4* yb4 = (const float4*)(y + M_TOT * DD);

    float4 va = ya4[((b * SS + i) << 6) + lane];
    const float4* pb = yb4 + ((b * SS + j) << 6) + lane;
    float4* po = (float4*)out + ((long long)r0 << 6) + lane;

    for (int r = r0; r < r1; ++r) {
        float4 vb = *pb;
        float4 o;
        o.x = va.x + vb.x; o.y = va.y + vb.y;
        o.z = va.z + vb.z; o.w = va.w + vb.w;
        *po = o;
        po += 64;
        // advance (wave-uniform)
        ++j;
        pb += 64;
        if (j == SS) {
            ++i;
            if (i == SS - 1) { ++b; i = 0; }
            j = i + 1;
            if (r + 1 < r1) {                 // guard: no OOB state load at slice end
                va = ya4[((b * SS + i) << 6) + lane];
                pb = yb4 + ((b * SS + j) << 6) + lane;
            }
        }
    }
}

extern "C" void kernel_launch(void* const* d_in, const int* in_sizes, int n_in,
                              void* d_out, int out_size, void* d_ws, size_t ws_size,
                              hipStream_t stream) {
    const float* x    = (const float*)d_in[0];   // (8,160,256)
    const float* W    = (const float*)d_in[1];   // (512,256)
    const float* bias = (const float*)d_in[2];   // (256,)
    float* y   = (float*)d_ws;                   // ya[1280*256] then yb[1280*256]
    float* out = (float*)d_out;                  // (8,12720,256)

    dim3 gemm_grid(512 / 64, 1280 / 32);         // 8 x 40 = 320 blocks
    gemm_kernel<<<gemm_grid, 256, 0, stream>>>(x, W, bias, y);

    expand_kernel<<<NWAVES / 4, 256, 0, stream>>>(y, out);
}